// Round 7
// baseline (726.911 us; speedup 1.0000x reference)
//
#include <hip/hip_runtime.h>
#include <hip/hip_bf16.h>

// GatherModel: 6-step NNConv message passing, reformulated:
//   agg[n,o] = sum_{ki} S[n,ki] * T'[ki,o]   (ki = k*42+i, K padded to 1824)
//   S[n] = sum_{e: dst=n} h'[e] (x) out[src[e]]
//   h'[e] = [relu(e_feat@en_w1+b1), 1]       (step-invariant)
// R7: FULL FUSION. One kernel per step, one block per 16-node tile:
//   phase1: S rows -> LDS (bf16, stride 1832 shorts: 16B-aligned b128,
//           2-way banks = free)
//   phase2: 57 K-step MFMA (K-range split over 4 waves), A from LDS,
//           B from pre-packed global fragments (layout proven in R6)
//   phase3: cross-wave reduce + residual + ReLU (LDS)
//   phase4: msg_w matvec + store.
// Kills Sb (37MBx2), aggP (16MBx2), mbuf per-step global round trips.

#define N_NODES 10000
#define N_EDGES 160000
#define D 42
#define DE 10
#define KH 43          // 42 + bias row
#define HP 44          // h row stride (11 x float4)
#define KI 1806        // 43*42
#define NKSTEP 57      // K-steps of 32 (K padded to 1824)
#define SSTR 1832      // sS row stride in shorts (16B-aligned, 2-way banks)
#define SCAP 16        // edges staged per chunk per wave

typedef __attribute__((ext_vector_type(8))) short short8;
typedef __attribute__((ext_vector_type(4))) float f32x4;

__global__ __launch_bounds__(256) void k_lin0(const float* __restrict__ nf,
        const float* __restrict__ w, const float* __restrict__ b,
        float* __restrict__ out) {
    int idx = blockIdx.x * 256 + threadIdx.x;
    if (idx >= N_NODES * D) return;
    int n = idx / D, j = idx % D;
    const float* row = nf + n * D;
    float acc = b[j];
    #pragma unroll
    for (int i = 0; i < D; ++i) acc = fmaf(row[i], w[i * D + j], acc);
    out[idx] = fmaxf(acc, 0.f);
}

// B-fragments: Bfr[((nt*57 + ks)*64 + lane)*8 + j] = bf16(T'[k][col]),
// col = nt*16 + (lane&15), k = ks*32 + (lane>>4)*8 + j. Zero outside range.
__global__ __launch_bounds__(256) void k_T2B(const float* __restrict__ w2,
        const float* __restrict__ b2, __hip_bfloat16* __restrict__ Bfr) {
    int idx = blockIdx.x * 256 + threadIdx.x;
    if (idx >= 3 * NKSTEP * 64 * 8) return;
    int j = idx & 7, lane = (idx >> 3) & 63;
    int ks = (idx >> 9) % NKSTEP, nt = idx / (NKSTEP * 512);
    int col = nt * 16 + (lane & 15);
    int k = ks * 32 + ((lane >> 4) * 8) + j;
    float v = 0.f;
    if (col < D && k < KI) {
        int kk = k / D, ii = k % D;
        v = (kk < D) ? w2[kk * (D * D) + ii * D + col] : b2[ii * D + col];
    }
    Bfr[idx] = __float2bfloat16(v);
}

__global__ __launch_bounds__(256) void k_hist(const int* __restrict__ dst,
        int* __restrict__ cnt) {
    int e = blockIdx.x * 256 + threadIdx.x;
    if (e < N_EDGES) atomicAdd(&cnt[dst[e]], 1);
}

__global__ __launch_bounds__(1024) void k_scan(const int* __restrict__ cnt,
        int* __restrict__ row_ptr, int* __restrict__ cursor) {
    __shared__ int buf[1024];
    __shared__ int s_run;
    const int t = threadIdx.x;
    if (t == 0) s_run = 0;
    __syncthreads();
    for (int base = 0; base < N_NODES; base += 1024) {
        int v = (base + t < N_NODES) ? cnt[base + t] : 0;
        buf[t] = v;
        __syncthreads();
        for (int off = 1; off < 1024; off <<= 1) {
            int add = (t >= off) ? buf[t - off] : 0;
            __syncthreads();
            buf[t] += add;
            __syncthreads();
        }
        int excl = buf[t] - v;
        if (base + t < N_NODES) {
            int val = s_run + excl;
            row_ptr[base + t] = val;
            cursor[base + t]  = val;
        }
        __syncthreads();
        if (t == 0) s_run += buf[1023];
        __syncthreads();
    }
    if (t == 0) { row_ptr[N_NODES] = s_run; cursor[N_NODES] = s_run; }
}

__global__ __launch_bounds__(256) void k_scatter(const int* __restrict__ dst,
        const int* __restrict__ src, int* __restrict__ cursor,
        int* __restrict__ srcp, int* __restrict__ pos) {
    int e = blockIdx.x * 256 + threadIdx.x;
    if (e < N_EDGES) {
        int p = atomicAdd(&cursor[dst[e]], 1);
        pos[e] = p;
        srcp[p] = src[e];
    }
}

// h' in permuted (CSR) order: hp[pos[e]] = [relu(ef@w1+b1), 1, 0]
__global__ __launch_bounds__(256) void k_h(const float* __restrict__ ef,
        const float* __restrict__ w1, const float* __restrict__ b1,
        const int* __restrict__ pos, float* __restrict__ hp) {
    int idx = blockIdx.x * 256 + threadIdx.x;
    if (idx >= N_EDGES * HP) return;
    int e = idx / HP, j = idx % HP;
    float v;
    if (j < D) {
        const float* row = ef + e * DE;
        float acc = b1[j];
        #pragma unroll
        for (int i = 0; i < DE; ++i) acc = fmaf(row[i], w1[i * D + j], acc);
        v = fmaxf(acc, 0.f);
    } else {
        v = (j == D) ? 1.0f : 0.0f;
    }
    hp[(size_t)pos[e] * HP + j] = v;
}

// Fused step: block = 256 threads (4 waves), 16 nodes (grid 625).
__global__ __launch_bounds__(256) void k_step(
        const float* __restrict__ hp, const float* __restrict__ out_in,
        const int* __restrict__ srcp, const int* __restrict__ row_ptr,
        const __hip_bfloat16* __restrict__ Bfr,
        const float* __restrict__ nf, const float* __restrict__ msg_w,
        const float* __restrict__ msg_b, const float* __restrict__ conv_b,
        float* __restrict__ out_dst, int last) {
    __shared__ __hip_bfloat16 sS[16 * SSTR];     // 58.6 KB
    __shared__ float sU[3840];                   // 15 KB: stage / red[4] + m
    const int t = threadIdx.x;
    const int wv = t >> 6;
    const int l = t & 63;
    const int n0 = blockIdx.x * 16;
    const bool act = (l < D);

    // zero K-pad cols 1806..1823 of all 16 S-rows
    for (int z = t; z < 16 * 18; z += 256)
        sS[(z / 18) * SSTR + KI + (z % 18)] = __float2bfloat16(0.f);

    // ---- phase 1: S rows for this wave's 4 nodes -> LDS ----
    float* stg = sU + wv * (SCAP * HP);          // per-wave staging slice
    for (int q = 0; q < 4; ++q) {
        const int nloc = wv * 4 + q;
        const int node = n0 + nloc;
        float acc[HP];
        #pragma unroll
        for (int k = 0; k < HP; ++k) acc[k] = 0.f;
        const int beg = row_ptr[node], end = row_ptr[node + 1];
        for (int base = beg; base < end; base += SCAP) {
            const int cnt = min(SCAP, end - base);
            const int nf4 = cnt * (HP / 4);
            for (int f = l; f < nf4; f += 64)
                *(float4*)&stg[f * 4] =
                    *(const float4*)(hp + (size_t)base * HP + f * 4);
            asm volatile("s_waitcnt lgkmcnt(0)" ::: "memory");
            float x0 = 0.f, x1 = 0.f;
            if (act) {
                x0 = out_in[srcp[base] * D + l];
                if (cnt > 1) x1 = out_in[srcp[base + 1] * D + l];
            }
            for (int j = 0; j < cnt; ++j) {
                float x2 = 0.f;
                if (act && j + 2 < cnt) x2 = out_in[srcp[base + j + 2] * D + l];
                #pragma unroll
                for (int m4 = 0; m4 < HP / 4; ++m4) {
                    float4 q4 = *(const float4*)&stg[j * HP + m4 * 4];
                    acc[4 * m4 + 0] = fmaf(q4.x, x0, acc[4 * m4 + 0]);
                    acc[4 * m4 + 1] = fmaf(q4.y, x0, acc[4 * m4 + 1]);
                    acc[4 * m4 + 2] = fmaf(q4.z, x0, acc[4 * m4 + 2]);
                    acc[4 * m4 + 3] = fmaf(q4.w, x0, acc[4 * m4 + 3]);
                }
                x0 = x1; x1 = x2;
            }
        }
        if (act) {
            #pragma unroll
            for (int k = 0; k < KH; ++k)
                sS[nloc * SSTR + k * D + l] = __float2bfloat16(acc[k]);
        }
    }
    __syncthreads();

    // ---- phase 2: MFMA, K-steps split 15/14/14/14 across waves ----
    const int ks0 = (wv == 0) ? 0 : (wv == 1) ? 15 : (wv == 2) ? 29 : 43;
    const int ks1 = (wv == 0) ? 15 : (wv == 1) ? 29 : (wv == 2) ? 43 : 57;
    f32x4 a0 = {0.f, 0.f, 0.f, 0.f};
    f32x4 a1 = {0.f, 0.f, 0.f, 0.f};
    f32x4 a2 = {0.f, 0.f, 0.f, 0.f};
    const short* sSrow = (const short*)sS + (l & 15) * SSTR + ((l >> 4) * 8);
    const short* bb = (const short*)Bfr + (size_t)l * 8;
    for (int ks = ks0; ks < ks1; ++ks) {
        short8 a  = *(const short8*)(sSrow + ks * 32);
        short8 b0 = *(const short8*)(bb + (size_t)(0 * NKSTEP + ks) * 512);
        short8 b1 = *(const short8*)(bb + (size_t)(1 * NKSTEP + ks) * 512);
        short8 b2 = *(const short8*)(bb + (size_t)(2 * NKSTEP + ks) * 512);
        a0 = __builtin_amdgcn_mfma_f32_16x16x32_bf16(a, b0, a0, 0, 0, 0);
        a1 = __builtin_amdgcn_mfma_f32_16x16x32_bf16(a, b1, a1, 0, 0, 0);
        a2 = __builtin_amdgcn_mfma_f32_16x16x32_bf16(a, b2, a2, 0, 0, 0);
    }
    // write partials: red[wv][nloc][col48]
    {
        float* red = sU + wv * 768;
        const int rl = (l >> 4) * 4, cl = l & 15;
        #pragma unroll
        for (int r = 0; r < 4; ++r) {
            red[(rl + r) * 48 + cl]      = a0[r];
            red[(rl + r) * 48 + 16 + cl] = a1[r];
            red[(rl + r) * 48 + 32 + cl] = a2[r];
        }
    }
    __syncthreads();

    // ---- phase 3: reduce + residual + ReLU -> m (sU+3072) ----
    for (int idx = t; idx < 768; idx += 256) {
        float v = sU[idx] + sU[768 + idx] + sU[1536 + idx] + sU[2304 + idx];
        int nl_ = idx / 48, o = idx % 48;
        float mv = 0.f;
        if (o < D) {
            v += out_in[(size_t)(n0 + nl_) * D + o] + conv_b[o];
            mv = fmaxf(v, 0.f);
        }
        sU[3072 + idx] = mv;
    }
    __syncthreads();

    // ---- phase 4: out' = relu(m @ msg_w + msg_b) [+ nf if last] ----
    const float* mB = sU + 3072;
    for (int idx = t; idx < 16 * D; idx += 256) {
        int nl_ = idx / D, pcol = idx % D;
        float s = msg_b[pcol];
        #pragma unroll 6
        for (int o = 0; o < D; ++o)
            s = fmaf(mB[nl_ * 48 + o], msg_w[o * D + pcol], s);
        float v = fmaxf(s, 0.f);
        const size_t gi = (size_t)(n0 + nl_) * D + pcol;
        if (last) v += nf[gi];
        out_dst[gi] = v;
    }
}

extern "C" void kernel_launch(void* const* d_in, const int* in_sizes, int n_in,
                              void* d_out, int out_size, void* d_ws, size_t ws_size,
                              hipStream_t stream) {
    const float* nf    = (const float*)d_in[0];
    const float* ef    = (const float*)d_in[1];
    const int*   src   = (const int*)d_in[2];
    const int*   dst   = (const int*)d_in[3];
    const float* lin0w = (const float*)d_in[4];
    const float* lin0b = (const float*)d_in[5];
    const float* msgw  = (const float*)d_in[6];
    const float* msgb  = (const float*)d_in[7];
    const float* enw1  = (const float*)d_in[8];
    const float* enb1  = (const float*)d_in[9];
    const float* enw2  = (const float*)d_in[10];
    const float* enb2  = (const float*)d_in[11];
    const float* convb = (const float*)d_in[12];

    // ws layout (~33 MB)
    char* p = (char*)d_ws;
    auto alloc = [&](size_t bytes) -> char* {
        char* r = p; p += (bytes + 255) & ~(size_t)255; return r;
    };
    float* outA = (float*)alloc((size_t)N_NODES * D * 4);
    float* outB = (float*)alloc((size_t)N_NODES * D * 4);
    float* hp   = (float*)alloc((size_t)N_EDGES * HP * 4);
    __hip_bfloat16* Bfr = (__hip_bfloat16*)alloc((size_t)3 * NKSTEP * 64 * 8 * 2);
    int* cnt    = (int*)alloc((N_NODES + 1) * 4);
    int* rowp   = (int*)alloc((N_NODES + 1) * 4);
    int* cur    = (int*)alloc((N_NODES + 1) * 4);
    int* srcp   = (int*)alloc((size_t)N_EDGES * 4);
    int* posb   = (int*)alloc((size_t)N_EDGES * 4);

    hipMemsetAsync(cnt, 0, (N_NODES + 1) * 4, stream);
    k_lin0<<<(N_NODES * D + 255) / 256, 256, 0, stream>>>(nf, lin0w, lin0b, outA);
    k_T2B<<<(3 * NKSTEP * 64 * 8 + 255) / 256, 256, 0, stream>>>(enw2, enb2, Bfr);
    k_hist<<<(N_EDGES + 255) / 256, 256, 0, stream>>>(dst, cnt);
    k_scan<<<1, 1024, 0, stream>>>(cnt, rowp, cur);
    k_scatter<<<(N_EDGES + 255) / 256, 256, 0, stream>>>(dst, src, cur, srcp, posb);
    k_h<<<(N_EDGES * HP + 255) / 256, 256, 0, stream>>>(ef, enw1, enb1, posb, hp);

    const int tiles = N_NODES / 16;               // 625 exactly
    float* bufs[2] = {outA, outB};
    for (int s_i = 0; s_i < 6; ++s_i) {
        const float* cin = bufs[s_i % 2];
        float* cout = bufs[(s_i + 1) % 2];
        int last = (s_i == 5) ? 1 : 0;
        k_step<<<tiles, 256, 0, stream>>>(hp, cin, srcp, rowp, Bfr,
                                          nf, msgw, msgb, convb,
                                          last ? (float*)d_out : cout, last);
    }
}

// Round 8
// 350.026 us; speedup vs baseline: 2.0767x; 2.0767x over previous
//
#include <hip/hip_runtime.h>
#include <hip/hip_bf16.h>

// GatherModel: 6-step NNConv message passing, reformulated:
//   agg[n,o] = sum_{ki} S[n,ki] * T'[ki,o]   (ki = k*42+i, K padded to 1824)
//   S[n]     = H_n^T @ X_n  (per-node GEMM over edges, K=deg!)  <-- R8
//   h'[e] = [relu(e_feat@en_w1+b1), 1]       (step-invariant, bf16)
// R8: phase 1 is now ALSO an MFMA GEMM: per 32-edge chunk, A = h'^T
// (coalesced 2B loads from bf16 hp, zero-masked past deg), B = gathered
// x (lane-parallel dword gathers + cvt), 9 MFMA -> S tile in registers,
// then one LDS transpose store. Kills the serial 44-FMA-per-edge chain
// that left R7 at 13% VALUBusy / 13% occupancy.
// Fragment conventions identical to R6-validated (A row=l&15, B col=l&15,
// k=(l>>4)*8+j both sides; C/D col=lane&15, row=(lane>>4)*4+reg).

#define N_NODES 10000
#define N_EDGES 160000
#define D 42
#define DE 10
#define XSTR 48        // out buffers stride (cols 42..47 = 0)
#define HSTR 48        // hp16 stride (col 42 = 1.0 bias, 43..47 = 0)
#define KI 1806        // 43*42
#define NKSTEP 57      // K-steps of 32 (K padded to 1824)
#define SSTR 1832      // sS row stride in shorts (16B-aligned)

typedef __attribute__((ext_vector_type(8))) short short8;
typedef __attribute__((ext_vector_type(4))) float f32x4;

static __device__ __forceinline__ short bf16b(float x) {
    __hip_bfloat16 h = __float2bfloat16(x);
    return *reinterpret_cast<short*>(&h);
}

__global__ __launch_bounds__(256) void k_lin0(const float* __restrict__ nf,
        const float* __restrict__ w, const float* __restrict__ b,
        float* __restrict__ out) {
    int idx = blockIdx.x * 256 + threadIdx.x;
    if (idx >= N_NODES * XSTR) return;
    int n = idx / XSTR, j = idx % XSTR;
    float v = 0.f;
    if (j < D) {
        const float* row = nf + n * D;
        float acc = b[j];
        #pragma unroll
        for (int i = 0; i < D; ++i) acc = fmaf(row[i], w[i * D + j], acc);
        v = fmaxf(acc, 0.f);
    }
    out[idx] = v;
}

// B-fragments for phase 2: Bfr[((nt*57+ks)*64+lane)*8+j] = bf16(T'[ki][col]),
// col = nt*16+(lane&15), ki = ks*32+(lane>>4)*8+j. Zero outside range.
__global__ __launch_bounds__(256) void k_T2B(const float* __restrict__ w2,
        const float* __restrict__ b2, __hip_bfloat16* __restrict__ Bfr) {
    int idx = blockIdx.x * 256 + threadIdx.x;
    if (idx >= 3 * NKSTEP * 64 * 8) return;
    int j = idx & 7, lane = (idx >> 3) & 63;
    int ks = (idx >> 9) % NKSTEP, nt = idx / (NKSTEP * 512);
    int col = nt * 16 + (lane & 15);
    int k = ks * 32 + ((lane >> 4) * 8) + j;
    float v = 0.f;
    if (col < D && k < KI) {
        int kk = k / D, ii = k % D;
        v = (kk < D) ? w2[kk * (D * D) + ii * D + col] : b2[ii * D + col];
    }
    Bfr[idx] = __float2bfloat16(v);
}

__global__ __launch_bounds__(256) void k_hist(const int* __restrict__ dst,
        int* __restrict__ cnt) {
    int e = blockIdx.x * 256 + threadIdx.x;
    if (e < N_EDGES) atomicAdd(&cnt[dst[e]], 1);
}

__global__ __launch_bounds__(1024) void k_scan(const int* __restrict__ cnt,
        int* __restrict__ row_ptr, int* __restrict__ cursor) {
    __shared__ int buf[1024];
    __shared__ int s_run;
    const int t = threadIdx.x;
    if (t == 0) s_run = 0;
    __syncthreads();
    for (int base = 0; base < N_NODES; base += 1024) {
        int v = (base + t < N_NODES) ? cnt[base + t] : 0;
        buf[t] = v;
        __syncthreads();
        for (int off = 1; off < 1024; off <<= 1) {
            int add = (t >= off) ? buf[t - off] : 0;
            __syncthreads();
            buf[t] += add;
            __syncthreads();
        }
        int excl = buf[t] - v;
        if (base + t < N_NODES) {
            int val = s_run + excl;
            row_ptr[base + t] = val;
            cursor[base + t]  = val;
        }
        __syncthreads();
        if (t == 0) s_run += buf[1023];
        __syncthreads();
    }
    if (t == 0) { row_ptr[N_NODES] = s_run; cursor[N_NODES] = s_run; }
}

__global__ __launch_bounds__(256) void k_scatter(const int* __restrict__ dst,
        const int* __restrict__ src, int* __restrict__ cursor,
        int* __restrict__ srcp, int* __restrict__ pos) {
    int e = blockIdx.x * 256 + threadIdx.x;
    if (e < N_EDGES) {
        int p = atomicAdd(&cursor[dst[e]], 1);
        pos[e] = p;
        srcp[p] = src[e];
    }
}

// h' in CSR order, bf16, stride 48: [relu(ef@w1+b1)(42), 1.0, 0,0,0,0,0]
__global__ __launch_bounds__(256) void k_h16(const float* __restrict__ ef,
        const float* __restrict__ w1, const float* __restrict__ b1,
        const int* __restrict__ pos, __hip_bfloat16* __restrict__ hp16) {
    int idx = blockIdx.x * 256 + threadIdx.x;
    if (idx >= N_EDGES * HSTR) return;
    int e = idx / HSTR, j = idx % HSTR;
    float v;
    if (j < D) {
        const float* row = ef + e * DE;
        float acc = b1[j];
        #pragma unroll
        for (int i = 0; i < DE; ++i) acc = fmaf(row[i], w1[i * D + j], acc);
        v = fmaxf(acc, 0.f);
    } else {
        v = (j == D) ? 1.0f : 0.0f;
    }
    hp16[(size_t)pos[e] * HSTR + j] = __float2bfloat16(v);
}

#define MFMA(A, B, C) C = __builtin_amdgcn_mfma_f32_16x16x32_bf16(A, B, C, 0, 0, 0)

// Fused step: 512 threads (8 waves), 16 nodes per block, grid 625.
__global__ __launch_bounds__(512) void k_step2(
        const __hip_bfloat16* __restrict__ hp16, const float* __restrict__ out_in,
        const int* __restrict__ srcp, const int* __restrict__ row_ptr,
        const __hip_bfloat16* __restrict__ Bfr,
        const float* __restrict__ nf, const float* __restrict__ msg_w,
        const float* __restrict__ msg_b, const float* __restrict__ conv_b,
        float* __restrict__ out_dst, int last) {
    __shared__ __align__(16) __hip_bfloat16 sS[16 * SSTR];  // 58.6 KB
    __shared__ float sR[16 * 48];                           // 3 KB
    __shared__ float sM[16 * 48];                           // 3 KB
    const int t = threadIdx.x;
    const int wv = t >> 6;
    const int l = t & 63;
    const int g = l >> 4;          // lane quarter-group 0..3
    const int cl = l & 15;
    const int n0 = blockIdx.x * 16;

    for (int i = t; i < 16 * 48; i += 512) sR[i] = 0.f;
    for (int i = t; i < 16 * 18; i += 512)                  // zero ki pads
        sS[(i / 18) * SSTR + KI + (i % 18)] = __float2bfloat16(0.f);

    // ---- phase 1: per-node S = h'^T @ X via MFMA (2 nodes per wave) ----
    const short* hp_s = (const short*)hp16;
    for (int q = 0; q < 2; ++q) {
        const int nloc = wv * 2 + q;
        const int node = n0 + nloc;
        const int beg = row_ptr[node], end = row_ptr[node + 1];
        f32x4 c00 = {0.f,0.f,0.f,0.f}, c01 = c00, c02 = c00;
        f32x4 c10 = c00, c11 = c00, c12 = c00;
        f32x4 c20 = c00, c21 = c00, c22 = c00;
        for (int e0 = beg; e0 < end; e0 += 32) {
            short8 a0, a1, a2, b0, b1, b2;
            #pragma unroll
            for (int j = 0; j < 8; ++j) {
                int ppos = e0 + g * 8 + j;
                bool vld = ppos < end;
                int pc = vld ? ppos : end - 1;
                const short* hr = hp_s + (size_t)pc * HSTR + cl;
                short h0 = hr[0], h1 = hr[16], h2 = hr[32];
                a0[j] = vld ? h0 : (short)0;
                a1[j] = vld ? h1 : (short)0;
                a2[j] = vld ? h2 : (short)0;
                const float* xr = out_in + (size_t)srcp[pc] * XSTR + cl;
                b0[j] = bf16b(xr[0]);
                b1[j] = bf16b(xr[16]);
                b2[j] = bf16b(xr[32]);
            }
            MFMA(a0, b0, c00); MFMA(a0, b1, c01); MFMA(a0, b2, c02);
            MFMA(a1, b0, c10); MFMA(a1, b1, c11); MFMA(a1, b2, c12);
            MFMA(a2, b0, c20); MFMA(a2, b1, c21); MFMA(a2, b2, c22);
        }
        // C -> sS[nloc][ki = m*42 + col], m = k-row, col = i
        #define ST(ACC, MT, NT)                                              \
            _Pragma("unroll")                                                \
            for (int r = 0; r < 4; ++r) {                                    \
                int m = (MT) * 16 + g * 4 + r;                               \
                int col = (NT) * 16 + cl;                                    \
                if (m < 43 && col < D)                                       \
                    sS[nloc * SSTR + m * D + col] = __float2bfloat16(ACC[r]);\
            }
        ST(c00, 0, 0) ST(c01, 0, 1) ST(c02, 0, 2)
        ST(c10, 1, 0) ST(c11, 1, 1) ST(c12, 1, 2)
        ST(c20, 2, 0) ST(c21, 2, 1) ST(c22, 2, 2)
        #undef ST
    }
    __syncthreads();

    // ---- phase 2: agg = S @ T' (57 K-steps split 8/7x7 across waves) ----
    {
        const int ks0 = (wv == 0) ? 0 : (wv * 7 + 1);
        const int ks1 = wv * 7 + 8;
        f32x4 d0 = {0.f,0.f,0.f,0.f}, d1 = d0, d2 = d0;
        const short* sSrow = (const short*)sS + cl * SSTR + g * 8;
        const short* bb = (const short*)Bfr + (size_t)l * 8;
        for (int ks = ks0; ks < ks1; ++ks) {
            short8 a  = *(const short8*)(sSrow + ks * 32);
            short8 B0 = *(const short8*)(bb + (size_t)(0 * NKSTEP + ks) * 512);
            short8 B1 = *(const short8*)(bb + (size_t)(1 * NKSTEP + ks) * 512);
            short8 B2 = *(const short8*)(bb + (size_t)(2 * NKSTEP + ks) * 512);
            MFMA(a, B0, d0); MFMA(a, B1, d1); MFMA(a, B2, d2);
        }
        const int rl = g * 4;
        #pragma unroll
        for (int r = 0; r < 4; ++r) {
            atomicAdd(&sR[(rl + r) * 48 + cl],      d0[r]);
            atomicAdd(&sR[(rl + r) * 48 + 16 + cl], d1[r]);
            atomicAdd(&sR[(rl + r) * 48 + 32 + cl], d2[r]);
        }
    }
    __syncthreads();

    // ---- phase 3: m = relu(agg + out_in + conv_b); stage msg_w -> sW ----
    float* sW = (float*)sS;                      // sS dead after phase 2
    for (int i = t; i < D * D; i += 512) sW[i] = msg_w[i];
    for (int idx = t; idx < 16 * 48; idx += 512) {
        int nl_ = idx / 48, o = idx % 48;
        float mv = 0.f;
        if (o < D) {
            float v = sR[idx] + out_in[(size_t)(n0 + nl_) * XSTR + o] + conv_b[o];
            mv = fmaxf(v, 0.f);
        }
        sM[idx] = mv;
    }
    __syncthreads();

    // ---- phase 4: out' = relu(m @ msg_w + msg_b) [+ nf if last] ----
    for (int idx = t; idx < 16 * 48; idx += 512) {
        int nl_ = idx / 48, pcol = idx % 48;
        if (pcol < D) {
            float s = msg_b[pcol];
            #pragma unroll 6
            for (int o = 0; o < D; ++o)
                s = fmaf(sM[nl_ * 48 + o], sW[o * D + pcol], s);
            float v = fmaxf(s, 0.f);
            if (last) {
                v += nf[(size_t)(n0 + nl_) * D + pcol];
                out_dst[(size_t)(n0 + nl_) * D + pcol] = v;   // compact 42
            } else {
                out_dst[(size_t)(n0 + nl_) * XSTR + pcol] = v;
            }
        } else if (!last) {
            out_dst[(size_t)(n0 + nl_) * XSTR + pcol] = 0.f;  // keep pads zero
        }
    }
}

extern "C" void kernel_launch(void* const* d_in, const int* in_sizes, int n_in,
                              void* d_out, int out_size, void* d_ws, size_t ws_size,
                              hipStream_t stream) {
    const float* nf    = (const float*)d_in[0];
    const float* ef    = (const float*)d_in[1];
    const int*   src   = (const int*)d_in[2];
    const int*   dst   = (const int*)d_in[3];
    const float* lin0w = (const float*)d_in[4];
    const float* lin0b = (const float*)d_in[5];
    const float* msgw  = (const float*)d_in[6];
    const float* msgb  = (const float*)d_in[7];
    const float* enw1  = (const float*)d_in[8];
    const float* enb1  = (const float*)d_in[9];
    const float* enw2  = (const float*)d_in[10];
    const float* enb2  = (const float*)d_in[11];
    const float* convb = (const float*)d_in[12];

    // ws layout (~22 MB)
    char* p = (char*)d_ws;
    auto alloc = [&](size_t bytes) -> char* {
        char* r = p; p += (bytes + 255) & ~(size_t)255; return r;
    };
    float* outA = (float*)alloc((size_t)N_NODES * XSTR * 4);
    float* outB = (float*)alloc((size_t)N_NODES * XSTR * 4);
    __hip_bfloat16* hp16 = (__hip_bfloat16*)alloc((size_t)N_EDGES * HSTR * 2);
    __hip_bfloat16* Bfr  = (__hip_bfloat16*)alloc((size_t)3 * NKSTEP * 64 * 8 * 2);
    int* cnt    = (int*)alloc((N_NODES + 1) * 4);
    int* rowp   = (int*)alloc((N_NODES + 1) * 4);
    int* cur    = (int*)alloc((N_NODES + 1) * 4);
    int* srcp   = (int*)alloc((size_t)N_EDGES * 4);
    int* posb   = (int*)alloc((size_t)N_EDGES * 4);

    hipMemsetAsync(cnt, 0, (N_NODES + 1) * 4, stream);
    k_lin0<<<(N_NODES * XSTR + 255) / 256, 256, 0, stream>>>(nf, lin0w, lin0b, outA);
    k_T2B<<<(3 * NKSTEP * 64 * 8 + 255) / 256, 256, 0, stream>>>(enw2, enb2, Bfr);
    k_hist<<<(N_EDGES + 255) / 256, 256, 0, stream>>>(dst, cnt);
    k_scan<<<1, 1024, 0, stream>>>(cnt, rowp, cur);
    k_scatter<<<(N_EDGES + 255) / 256, 256, 0, stream>>>(dst, src, cur, srcp, posb);
    k_h16<<<(N_EDGES * HSTR + 255) / 256, 256, 0, stream>>>(ef, enw1, enb1, posb, hp16);

    const int tiles = N_NODES / 16;               // 625 exactly
    float* bufs[2] = {outA, outB};
    for (int s_i = 0; s_i < 6; ++s_i) {
        const float* cin = bufs[s_i % 2];
        float* cout = bufs[(s_i + 1) % 2];
        int last = (s_i == 5) ? 1 : 0;
        k_step2<<<tiles, 512, 0, stream>>>(hp16, cin, srcp, rowp, Bfr,
                                           nf, msgw, msgb, convb,
                                           last ? (float*)d_out : cout, last);
    }
}